// Round 6
// baseline (198.440 us; speedup 1.0000x reference)
//
#include <hip/hip_runtime.h>
#include <hip/hip_bf16.h>
#include <math.h>

#define NB 128   // batch
#define NR 36    // regions
#define NW 32    // words
#define ND 256   // feature dim

#define MARGINf 0.05f
#define TEMPf   14.0f
#define LAMf    9.0f
#define EPSf    1e-8f

typedef _Float16 f16x8 __attribute__((ext_vector_type(8)));
typedef _Float16 f16x4 __attribute__((ext_vector_type(4)));
typedef float    f32x4 __attribute__((ext_vector_type(4)));

// ================= workspace layout (float offsets) =================
#define WS_SCORES 0
#define WS_N1     16384
#define WS_GH     20480                  // f16[128][48*72] rows/cols >=36 zero
#define GH_ELEMS  (48 * 72)              // 3456 f16 per image
#define WS_IMH    241664                 // f16[128][48][256], rows 36..47 zero
#define WS_SH     1028096                // f16[128][32][256], word-masked
#define WS_NEED_BYTES ((size_t)1552384 * 4)   // ~6.2 MB

// ================= fallback workspace layout =================
#define G_STRIDE  40
#define FB_WS_G   (NB * NB)
#define FB_WS_N1  (FB_WS_G + NB * NR * G_STRIDE)
#define HS 264

// =====================================================================
// prep3: f16 conversions (imh zero-padded, sh word-masked), Gram f16, n1
// =====================================================================
__global__ __launch_bounds__(256) void prep3_kernel(
    const float* __restrict__ im, const float* __restrict__ s,
    const int* __restrict__ s_l, float* __restrict__ ws)
{
    const int b = blockIdx.x;
    const int t = threadIdx.x;
    __shared__ float s_imf[NR * 260];

    const float4* im4 = (const float4*)(im + (size_t)b * NR * ND);
    for (int i = t; i < NR * 64; i += 256) {
        int r = i >> 6, c4 = i & 63;
        *(float4*)&s_imf[r * 260 + 4 * c4] = im4[i];
    }
    // zero G region (1728 u32)
    unsigned int* Gz = (unsigned int*)((_Float16*)(ws + WS_GH) + (size_t)b * GH_ELEMS);
    for (int i = t; i < GH_ELEMS / 2; i += 256) Gz[i] = 0u;
    __syncthreads();

    // Gram f16 [48][72], fill 36x36
    _Float16* Gh = (_Float16*)(ws + WS_GH) + (size_t)b * GH_ELEMS;
    for (int i = t; i < NR * NR; i += 256) {
        int r = i / NR, rp = i - r * NR;
        const float4* a  = (const float4*)&s_imf[r * 260];
        const float4* bb = (const float4*)&s_imf[rp * 260];
        float acc = 0.f;
        for (int k = 0; k < 64; ++k) {
            float4 x = a[k], y = bb[k];
            acc += x.x * y.x + x.y * y.y + x.z * y.z + x.w * y.w;
        }
        Gh[r * 72 + rp] = (_Float16)acc;
    }

    // imh f16 [48][256], rows 36..47 zero
    _Float16* imh = (_Float16*)(ws + WS_IMH) + (size_t)b * 48 * 256;
    for (int i = t; i < 48 * 32; i += 256) {
        int r = i >> 5, ch = i & 31;
        f16x8 h;
        if (r < NR) {
            const float4 a  = *(const float4*)&s_imf[r * 260 + ch * 8];
            const float4 bb = *(const float4*)&s_imf[r * 260 + ch * 8 + 4];
            h[0] = (_Float16)a.x;  h[1] = (_Float16)a.y;
            h[2] = (_Float16)a.z;  h[3] = (_Float16)a.w;
            h[4] = (_Float16)bb.x; h[5] = (_Float16)bb.y;
            h[6] = (_Float16)bb.z; h[7] = (_Float16)bb.w;
        } else {
#pragma unroll
            for (int k = 0; k < 8; ++k) h[k] = (_Float16)0.f;
        }
        *(f16x8*)&imh[r * 256 + ch * 8] = h;
    }

    // sh f16 [32][256], word-masked
    const int sl = s_l[b];
    _Float16* sh = (_Float16*)(ws + WS_SH) + (size_t)b * NW * 256;
    const float4* s4 = (const float4*)(s + (size_t)b * NW * ND);
    for (int i = t; i < NW * 32; i += 256) {
        int w = i >> 5, ch = i & 31;
        f16x8 h;
        if (w < sl) {
            const float4 a  = s4[w * 64 + ch * 2];
            const float4 bb = s4[w * 64 + ch * 2 + 1];
            h[0] = (_Float16)a.x;  h[1] = (_Float16)a.y;
            h[2] = (_Float16)a.z;  h[3] = (_Float16)a.w;
            h[4] = (_Float16)bb.x; h[5] = (_Float16)bb.y;
            h[6] = (_Float16)bb.z; h[7] = (_Float16)bb.w;
        } else {
#pragma unroll
            for (int k = 0; k < 8; ++k) h[k] = (_Float16)0.f;
        }
        *(f16x8*)&sh[w * 256 + ch * 8] = h;
    }

    // n1[b][w]
    {
        const int w = t >> 3, g = t & 7;
        float acc = 0.f;
        for (int j = 0; j < 8; ++j) {
            float4 v = s4[w * 64 + g * 8 + j];
            acc += v.x * v.x + v.y * v.y + v.z * v.z + v.w * v.w;
        }
        acc += __shfl_down(acc, 4, 8);
        acc += __shfl_down(acc, 2, 8);
        acc += __shfl_down(acc, 1, 8);
        if (g == 0) ws[WS_N1 + b * NW + w] = sqrtf(acc);
    }
}

// =====================================================================
// fused: A0 register-GEMM + leaky/norm/softmax + n2 MFMA + scores
// block = (image b, 8 captions = 256 cols); grid (16, 128)
// =====================================================================
__global__ __launch_bounds__(256, 4) void fused_kernel(
    const int* __restrict__ s_l, const float* __restrict__ im_mask,
    float* __restrict__ ws)
{
    const int n0 = blockIdx.x * 256;
    const int b  = blockIdx.y;
    const int t  = threadIdx.x;
    const int wave = t >> 6, lane = t & 63;
    const int lm = lane & 15, kg = lane >> 4;

    // one shared buffer: first raw A0 tile [36][264] f16, later E tile [256][72] f16
    __shared__ _Float16 s_buf[256 * 72];   // 36,864 B
    __shared__ float s_coef[288];
    __shared__ float s_n2[256];
    __shared__ float s_m[NR];
    __shared__ int   s_sl[8];
    _Float16* s_rawh = s_buf;
    _Float16* s_E    = s_buf;

    const _Float16* imh = (const _Float16*)(ws + WS_IMH) + (size_t)b * 48 * 256;
    const _Float16* sh  = (const _Float16*)(ws + WS_SH);
    const _Float16* Gg  = (const _Float16*)(ws + WS_GH) + (size_t)b * GH_ELEMS;

    const float n1v = ws[WS_N1 + n0 + t];
    if (t < NR) s_m[t] = im_mask[b * NR + t];
    if (t < 8)  s_sl[t] = s_l[(n0 >> 5) + t];

    // ---- phase 1: A0 tile 48x256, K=256, all operands direct from global ----
    f32x4 acc[3][4];
#pragma unroll
    for (int mt = 0; mt < 3; ++mt)
#pragma unroll
        for (int nt = 0; nt < 4; ++nt) acc[mt][nt] = (f32x4){0.f, 0.f, 0.f, 0.f};

    const _Float16* aBase = imh + lm * 256 + kg * 8;
    const _Float16* bBase = sh + (size_t)(n0 + wave * 64 + lm) * 256 + kg * 8;
#pragma unroll
    for (int ks = 0; ks < 8; ++ks) {
        f16x8 af[3], bf[4];
#pragma unroll
        for (int mt = 0; mt < 3; ++mt)
            af[mt] = *(const f16x8*)(aBase + mt * 16 * 256 + ks * 32);
#pragma unroll
        for (int nt = 0; nt < 4; ++nt)
            bf[nt] = *(const f16x8*)(bBase + nt * 16 * 256 + ks * 32);
#pragma unroll
        for (int mt = 0; mt < 3; ++mt)
#pragma unroll
            for (int nt = 0; nt < 4; ++nt)
                acc[mt][nt] = __builtin_amdgcn_mfma_f32_16x16x32_f16(af[mt], bf[nt], acc[mt][nt], 0, 0, 0);
    }

    // ---- phase 2: acc -> raw tile [r][264] f16 (r<36) ----
#pragma unroll
    for (int mt = 0; mt < 3; ++mt) {
#pragma unroll
        for (int nt = 0; nt < 4; ++nt) {
#pragma unroll
            for (int v = 0; v < 4; ++v) {
                const int r = mt * 16 + kg * 4 + v;
                if (r < NR)
                    s_rawh[r * 264 + wave * 64 + nt * 16 + lm] = (_Float16)acc[mt][nt][v];
            }
        }
    }
    __syncthreads();

    // ---- preload own column into registers (raw dies after this phase) ----
    float rawf[NR];
#pragma unroll
    for (int r = 0; r < NR; ++r) rawf[r] = (float)s_rawh[r * 264 + t];

    // ---- coef pass: per (r, caption): LAM / (||X||_w + eps) ----
    for (int i = t; i < NR * 8; i += 256) {
        const int r = i >> 3, p = i & 7;
        const float one_m = 1.f - s_m[r];
        float ss = 0.f;
        const _Float16* row = &s_rawh[r * 264 + p * 32];
#pragma unroll
        for (int j = 0; j < 4; ++j) {
            f16x8 h = *(const f16x8*)(row + 8 * j);
#pragma unroll
            for (int k2 = 0; k2 < 8; ++k2) {
                float raw = (float)h[k2];
                float X = (raw >= 0.f ? raw : 0.1f * raw) + one_m;
                ss += X * X;
            }
        }
        s_coef[i] = LAMf / (sqrtf(ss) + EPSf);
    }
    __syncthreads();   // raw fully consumed; E may overwrite buffer

    // ---- pass B: E = exp(X*coef)*m (den/w12 in regs), write E [n][72] ----
    float den = 0.f, W = 0.f;
    {
        const int p = t >> 5;
#pragma unroll
        for (int r4 = 0; r4 < 9; ++r4) {
            f16x4 pk;
#pragma unroll
            for (int j = 0; j < 4; ++j) {
                const int r = r4 * 4 + j;
                float raw = rawf[r];
                float mm = s_m[r];
                float X = (raw >= 0.f ? raw : 0.1f * raw) + (1.f - mm);
                float E = __expf(X * s_coef[r * 8 + p]) * mm;
                den += E;
                W += E * raw;
                pk[j] = (_Float16)E;
            }
            *(f16x4*)&s_E[t * 72 + r4 * 4] = pk;
        }
        f16x4 z4; z4[0] = z4[1] = z4[2] = z4[3] = (_Float16)0.f;
#pragma unroll
        for (int j = 9; j < 16; ++j) *(f16x4*)&s_E[t * 72 + 4 * j] = z4;
    }
    __syncthreads();

    // ---- n2 MFMA: D[n][r'] = sum_k E[n][k] G[r'][k] (K=64), n2 = sum D*E ----
    {
        f32x4 d[4][3];
#pragma unroll
        for (int tt = 0; tt < 4; ++tt)
#pragma unroll
            for (int rt = 0; rt < 3; ++rt) d[tt][rt] = (f32x4){0.f, 0.f, 0.f, 0.f};
#pragma unroll
        for (int ks = 0; ks < 2; ++ks) {
            f16x8 af[4], bf[3];
#pragma unroll
            for (int tt = 0; tt < 4; ++tt)
                af[tt] = *(const f16x8*)&s_E[(wave * 64 + tt * 16 + lm) * 72 + ks * 32 + kg * 8];
#pragma unroll
            for (int rt = 0; rt < 3; ++rt)
                bf[rt] = *(const f16x8*)(Gg + (rt * 16 + lm) * 72 + ks * 32 + kg * 8);
#pragma unroll
            for (int tt = 0; tt < 4; ++tt)
#pragma unroll
                for (int rt = 0; rt < 3; ++rt)
                    d[tt][rt] = __builtin_amdgcn_mfma_f32_16x16x32_f16(af[tt], bf[rt], d[tt][rt], 0, 0, 0);
        }
#pragma unroll
        for (int tt = 0; tt < 4; ++tt) {
#pragma unroll
            for (int v = 0; v < 4; ++v) {
                const int n = wave * 64 + tt * 16 + kg * 4 + v;
                float p2 = 0.f;
#pragma unroll
                for (int rt = 0; rt < 3; ++rt)
                    p2 += d[tt][rt][v] * (float)s_E[n * 72 + rt * 16 + lm];
                p2 += __shfl_xor(p2, 1, 16);
                p2 += __shfl_xor(p2, 2, 16);
                p2 += __shfl_xor(p2, 4, 16);
                p2 += __shfl_xor(p2, 8, 16);
                if (lm == 0) s_n2[n] = p2;
            }
        }
    }
    __syncthreads();

    // ---- final: cos (softmax denominators cancel), caption-sum, score ----
    {
        const int w = t & 31, p = t >> 5;
        const float n2 = fmaxf(s_n2[t], 0.f);
        const float cosv = W / fmaxf(n1v * sqrtf(n2), EPSf * den);
        const int sl = s_sl[p];
        float val = (w < sl) ? cosv : 0.f;
        val += __shfl_xor(val, 1, 32);
        val += __shfl_xor(val, 2, 32);
        val += __shfl_xor(val, 4, 32);
        val += __shfl_xor(val, 8, 32);
        val += __shfl_xor(val, 16, 32);
        if (w == 0) ws[WS_SCORES + b * NB + (n0 >> 5) + p] = val / (float)sl;
    }
}

// =====================================================================
// FALLBACK PATH (used only if ws_size too small)
// =====================================================================
__global__ __launch_bounds__(256) void prep_fb_kernel(
    const float* __restrict__ im, const float* __restrict__ s,
    float* __restrict__ ws)
{
    const int b = blockIdx.x;
    const int t = threadIdx.x;
    __shared__ float s_imf[NR * 260];

    const float4* im4 = (const float4*)(im + (size_t)b * NR * ND);
    for (int i = t; i < NR * (ND / 4); i += 256) {
        int r = i >> 6, c4 = i & 63;
        *(float4*)&s_imf[r * 260 + 4 * c4] = im4[i];
    }
    __syncthreads();

    float* G = ws + FB_WS_G + (size_t)b * NR * G_STRIDE;
    for (int i = t; i < NR * NR; i += 256) {
        int r = i / NR, rp = i - r * NR;
        const float4* a  = (const float4*)&s_imf[r * 260];
        const float4* bb = (const float4*)&s_imf[rp * 260];
        float acc = 0.f;
        for (int k = 0; k < ND / 4; ++k) {
            float4 x = a[k], y = bb[k];
            acc += x.x * y.x + x.y * y.y + x.z * y.z + x.w * y.w;
        }
        G[r * G_STRIDE + rp] = acc;
    }

    const int w = t >> 3, g = t & 7;
    const float4* s4 = (const float4*)(s + (size_t)b * NW * ND);
    float acc = 0.f;
    for (int j = 0; j < 8; ++j) {
        float4 v = s4[w * 64 + g * 8 + j];
        acc += v.x * v.x + v.y * v.y + v.z * v.z + v.w * v.w;
    }
    acc += __shfl_down(acc, 4, 8);
    acc += __shfl_down(acc, 2, 8);
    acc += __shfl_down(acc, 1, 8);
    if (g == 0) ws[FB_WS_N1 + b * NW + w] = sqrtf(acc);
}

__global__ __launch_bounds__(384) void scores_fb_kernel(
    const float* __restrict__ im, const float* __restrict__ s,
    const int* __restrict__ s_l, const float* __restrict__ im_mask,
    float* __restrict__ ws)
{
    const int c = blockIdx.x;
    const int b = blockIdx.y;
    const int t = threadIdx.x;

    __shared__ _Float16 s_imh[48 * HS];
    __shared__ _Float16 s_caph[NW * HS];
    __shared__ float s_A0[NR * 33];
    __shared__ float s_X[NR * 33];
    __shared__ float s_y[NW * 40];
    __shared__ float s_Gf[NR * G_STRIDE];
    __shared__ float s_nrm[NR];
    __shared__ float s_m[NR];
    __shared__ float s_p1[NW * 12];
    __shared__ float s_p2[NW * 12];

    const int sl = s_l[c];

    const float4* im4 = (const float4*)(im + (size_t)b * NR * ND);
    for (int i = t; i < NR * 32; i += 384) {
        int r = i >> 5, ch = i & 31;
        float4 a  = im4[r * 64 + ch * 2];
        float4 bb = im4[r * 64 + ch * 2 + 1];
        f16x8 h;
        h[0] = (_Float16)a.x;  h[1] = (_Float16)a.y;
        h[2] = (_Float16)a.z;  h[3] = (_Float16)a.w;
        h[4] = (_Float16)bb.x; h[5] = (_Float16)bb.y;
        h[6] = (_Float16)bb.z; h[7] = (_Float16)bb.w;
        *(f16x8*)&s_imh[r * HS + ch * 8] = h;
    }
    {
        unsigned int* z = (unsigned int*)&s_imh[NR * HS];
        for (int i = t; i < 12 * (HS / 2); i += 384) z[i] = 0u;
    }
    const float4* s4 = (const float4*)(s + (size_t)c * NW * ND);
    for (int i = t; i < NW * 32; i += 384) {
        int w = i >> 5, ch = i & 31;
        f16x8 h;
        if (w < sl) {
            float4 a  = s4[w * 64 + ch * 2];
            float4 bb = s4[w * 64 + ch * 2 + 1];
            h[0] = (_Float16)a.x;  h[1] = (_Float16)a.y;
            h[2] = (_Float16)a.z;  h[3] = (_Float16)a.w;
            h[4] = (_Float16)bb.x; h[5] = (_Float16)bb.y;
            h[6] = (_Float16)bb.z; h[7] = (_Float16)bb.w;
        } else {
#pragma unroll
            for (int k = 0; k < 8; ++k) h[k] = (_Float16)0.f;
        }
        *(f16x8*)&s_caph[w * HS + ch * 8] = h;
    }
    {
        const float4* Gg = (const float4*)(ws + FB_WS_G + (size_t)b * NR * G_STRIDE);
        float4* Gs = (float4*)s_Gf;
        for (int i = t; i < NR * 9; i += 384) {
            int r = i / 9, q = i - r * 9;
            Gs[r * 10 + q] = Gg[r * 10 + q];
        }
    }
    if (t < NR) s_m[t] = im_mask[b * NR + t];
    __syncthreads();

    {
        const int wave = t >> 6, lane = t & 63;
        const int r0 = (wave >> 1) * 16, w0 = (wave & 1) * 16;
        const int m = lane & 15, kg = lane >> 4;
        f32x4 acc = {0.f, 0.f, 0.f, 0.f};
        const _Float16* ap = &s_imh[(r0 + m) * HS + kg * 8];
        const _Float16* bp = &s_caph[(w0 + m) * HS + kg * 8];
#pragma unroll
        for (int ks = 0; ks < 8; ++ks) {
            f16x8 av = *(const f16x8*)(ap + ks * 32);
            f16x8 bv = *(const f16x8*)(bp + ks * 32);
            acc = __builtin_amdgcn_mfma_f32_16x16x32_f16(av, bv, acc, 0, 0, 0);
        }
        const int wcol = w0 + m;
        const int rbase = r0 + kg * 4;
#pragma unroll
        for (int v = 0; v < 4; ++v) {
            int r = rbase + v;
            if (r < NR) {
                float rawv = acc[v];
                s_A0[r * 33 + wcol] = rawv;
                float lk = rawv >= 0.f ? rawv : 0.1f * rawv;
                s_X[r * 33 + wcol] = lk + (1.f - s_m[r]);
            }
        }
    }
    __syncthreads();

    if (t < NR) {
        float sum = 0.f;
        for (int w = 0; w < NW; ++w) { float x = s_X[t * 33 + w]; sum += x * x; }
        s_nrm[t] = sqrtf(sum) + EPSf;
    }
    __syncthreads();

    if (t < NW) {
        float xs[NR];
        float mx = -1e30f;
#pragma unroll
        for (int r = 0; r < NR; ++r) {
            float a = s_X[r * 33 + t] / s_nrm[r] * s_m[r] * LAMf;
            xs[r] = a; mx = fmaxf(mx, a);
        }
        float sum = 0.f;
#pragma unroll
        for (int r = 0; r < NR; ++r) {
            float e = __expf(xs[r] - mx) * s_m[r];
            xs[r] = e; sum += e;
        }
        float inv = 1.f / sum;
#pragma unroll
        for (int r = 0; r < NR; ++r) s_y[t * 40 + r] = xs[r] * inv;
    }
    __syncthreads();

    if (t < 288) {
        const int w = t / 9, q = t - (t / 9) * 9;
        float4 y4 = *(const float4*)&s_y[w * 40 + q * 4];
        float4 acc4 = {0.f, 0.f, 0.f, 0.f};
        float w12p = 0.f;
#pragma unroll
        for (int r = 0; r < NR; ++r) {
            float yr = s_y[w * 40 + r];
            float4 g4 = *(const float4*)&s_Gf[r * G_STRIDE + q * 4];
            acc4.x += yr * g4.x; acc4.y += yr * g4.y;
            acc4.z += yr * g4.z; acc4.w += yr * g4.w;
        }
        float n2p = acc4.x * y4.x + acc4.y * y4.y + acc4.z * y4.z + acc4.w * y4.w;
#pragma unroll
        for (int k = 0; k < 4; ++k) {
            int r = q * 4 + k;
            w12p += s_y[w * 40 + r] * s_A0[r * 33 + w];
        }
        s_p1[w * 12 + q] = w12p;
        s_p2[w * 12 + q] = n2p;
    }
    __syncthreads();

    if (t < NW) {
        float w12v = 0.f, n2v = 0.f;
        for (int q = 0; q < 9; ++q) { w12v += s_p1[t * 12 + q]; n2v += s_p2[t * 12 + q]; }
        float n1v = ws[FB_WS_N1 + c * NW + t];
        float cosv = w12v / fmaxf(n1v * sqrtf(n2v), EPSf);
        float val = (t < sl) ? cosv : 0.f;
#pragma unroll
        for (int k = 16; k; k >>= 1) val += __shfl_down(val, k, 32);
        if (t == 0) ws[WS_SCORES + b * NB + c] = val / (float)sl;
    }
}

// ---------------- contrastive loss over 128x128 scores ----------------
__global__ __launch_bounds__(128) void loss_kernel(
    const float* __restrict__ scores, const int* __restrict__ qid,
    float* __restrict__ out)
{
    __shared__ int   s_q[NB];
    __shared__ float s_c[NB];
    __shared__ float s_v[NB];
    const int i = threadIdx.x;
    s_q[i] = qid[i];
    __syncthreads();

    const int q = s_q[i];
    bool dup = false;
    for (int j = 0; j < i; ++j) dup = dup || (s_q[j] == q);

    const float* row = scores + i * NB;
    float mx = -1e30f;
    for (int j = 0; j < NB; ++j) {
        float l = (row[j] - ((j == i) ? MARGINf : 0.f)) * TEMPf;
        mx = fmaxf(mx, l);
    }
    float sum = 0.f;
    for (int j = 0; j < NB; ++j) {
        float l = (row[j] - ((j == i) ? MARGINf : 0.f)) * TEMPf;
        sum += expf(l - mx);
    }
    const float logZ = mx + logf(sum);
    const float picked = (row[i] - MARGINf) * TEMPf;
    const float valid = dup ? 0.f : 1.f;
    s_c[i] = (logZ - picked) * valid;
    s_v[i] = valid;
    __syncthreads();
    if (i == 0) {
        float a = 0.f, v = 0.f;
        for (int j = 0; j < NB; ++j) { a += s_c[j]; v += s_v[j]; }
        out[0] = a / fmaxf(v, 1.f);
    }
}

extern "C" void kernel_launch(void* const* d_in, const int* in_sizes, int n_in,
                              void* d_out, int out_size, void* d_ws, size_t ws_size,
                              hipStream_t stream) {
    const float* im      = (const float*)d_in[0];
    const float* s       = (const float*)d_in[1];
    const int*   s_l     = (const int*)d_in[2];
    const float* im_mask = (const float*)d_in[3];
    const int*   qid     = (const int*)d_in[4];

    float* ws  = (float*)d_ws;
    float* out = (float*)d_out;

    if (ws_size >= WS_NEED_BYTES) {
        prep3_kernel<<<NB, 256, 0, stream>>>(im, s, s_l, ws);
        fused_kernel<<<dim3(16, NB), 256, 0, stream>>>(s_l, im_mask, ws);
    } else {
        prep_fb_kernel<<<NB, 256, 0, stream>>>(im, s, ws);
        dim3 grid(NB, NB);
        scores_fb_kernel<<<grid, 384, 0, stream>>>(im, s, s_l, im_mask, ws);
    }
    loss_kernel<<<1, 128, 0, stream>>>(ws + WS_SCORES, qid, out);
}